// Round 10
// baseline (175.699 us; speedup 1.0000x reference)
//
#include <hip/hip_runtime.h>

#define S_LEN 2048

typedef float f32x4 __attribute__((ext_vector_type(4)));
typedef int   i32x4 __attribute__((ext_vector_type(4)));
typedef int   i32x2 __attribute__((ext_vector_type(2)));

__device__ __forceinline__ float sin2pi(float rev){ float r; asm("v_sin_f32 %0, %1":"=v"(r):"v"(rev)); return r; }
__device__ __forceinline__ float cos2pi(float rev){ float r; asm("v_cos_f32 %0, %1":"=v"(r):"v"(rev)); return r; }
template<int M>
__device__ __forceinline__ float swz(float x){
  return __int_as_float(__builtin_amdgcn_ds_swizzle(__float_as_int(x), M));
}
template<int CTRL>
__device__ __forceinline__ float dppmov(float x){
  return __int_as_float(__builtin_amdgcn_update_dpp(0, __float_as_int(x), CTRL, 0xf, 0xf, false));
}

// lane layout (scan): half = l>>5 -> batch = bp*2+half; i = l&31; d(i) = ((i>>2)&7)|((i&3)<<3)
// => head(d) = d>>3 = i&3. Each lane holds BOTH h_r[d], h_i[d] (no cross-lane in h chain).
// K'' permutation: comb element k'' = 2*i + comp  <->  concat index comp*32 + d(i).
// W columns permuted identically in wprep, so the GEMM K-dot is invariant.

// ================= scan (blocks 0..255) + W-split prep (blocks 256..1279) =================
// 32 chunks x 64 steps, 128-step warm-up (validated R9 geometry; R3-validated step numerics).
// Decoupled gate pipeline: body(s) = P(s-1) | X(s-1) issue swizzle | H(s) pure-VALU | Z(s-2)
// consume swizzle (one full body of cover), sigmoid, m-update, packed store.
__global__ __launch_bounds__(64) void scan_kernel(
    const int* __restrict__ ids, const float* __restrict__ emb,
    const float* __restrict__ Wg, const float* __restrict__ bg,
    const float* __restrict__ dlg, const float* __restrict__ esc,
    ushort* __restrict__ chi, ushort* __restrict__ clo,
    const float* __restrict__ W32, ushort* __restrict__ whi, ushort* __restrict__ wlo)
{
  const int w = blockIdx.x;
  const int l = threadIdx.x;

  if (w >= 256){
    // ---- W_out -> bf16 hi/lo split with k'' = 2i+comp lane permutation ----
    int i0 = (w - 256) * 256 + l * 4;          // 4 consecutive k'' (i0 % 4 == 0)
    int v  = i0 >> 6;
    int ia = (i0 & 63) >> 1;                   // i for k''=i0, i0+1
    int ib = ia + 1;                           // i for k''=i0+2, i0+3
    int da = ((ia >> 2) & 7) | ((ia & 3) << 3);
    int db = ((ib >> 2) & 7) | ((ib & 3) << 3);
    float x0 = W32[v*64 + da], x1 = W32[v*64 + 32 + da];
    float x2 = W32[v*64 + db], x3 = W32[v*64 + 32 + db];
    unsigned hw01, hw23, lw01, lw23;
    asm("v_cvt_pk_bf16_f32 %0, %1, %2":"=v"(hw01):"v"(x0),"v"(x1));
    asm("v_cvt_pk_bf16_f32 %0, %1, %2":"=v"(hw23):"v"(x2),"v"(x3));
    float r0 = x0 - __uint_as_float(hw01 << 16);
    float r1 = x1 - __uint_as_float(hw01 & 0xffff0000u);
    float r2 = x2 - __uint_as_float(hw23 << 16);
    float r3 = x3 - __uint_as_float(hw23 & 0xffff0000u);
    asm("v_cvt_pk_bf16_f32 %0, %1, %2":"=v"(lw01):"v"(r0),"v"(r1));
    asm("v_cvt_pk_bf16_f32 %0, %1, %2":"=v"(lw23):"v"(r2),"v"(r3));
    *(i32x2*)(whi + i0) = (i32x2){(int)hw01, (int)hw23};
    *(i32x2*)(wlo + i0) = (i32x2){(int)lw01, (int)lw23};
    return;
  }

  const int c  = w >> 3;            // chunk 0..31
  const int bp = w & 7;             // batch pair
  const int half = l >> 5;
  const int b  = bp*2 + half;
  const int i  = l & 31;
  const int d  = ((i >> 2) & 7) | ((i & 3) << 3);
  const bool b0 = (l & 1) != 0;
  const bool b1 = (l & 2) != 0;

  const float es  = esc[0];
  const int hd = l & 3;
  const float dk  = 1.f/(1.f + __expf(-dlg[hd]));
  const float bgl = bg[hd];
  const f32x4 wgr = *(const f32x4*)(Wg + d*4);        // rows for h_r[d]
  const f32x4 wgi = *(const f32x4*)(Wg + (32+d)*4);   // rows for h_i[d]

  const int s0   = c*64;
  const int sw   = (s0 >= 128) ? (s0 - 128) : 0;
  const int send = s0 + 64;
  const int nq   = (send - sw) >> 2;

  const int* idb = ids + b*S_LEN;
  unsigned* pco = (unsigned*)chi + (size_t)b*S_LEN*32 + i;
  unsigned* plo = (unsigned*)clo + (size_t)b*S_LEN*32 + i;

  const float PHI_F   = 1.6180339887498949f;
  const float TWOPI_F = 6.283185307179586f;
  const float INV2PI  = 0.15915494309189535f;

  float hr = 0.f, hi = 0.f, mr = 0.f, mi = 0.f;
  float h2r = 0.f, h2i = 0.f;   // h(s-2)
  float mmB = 0.f, swB = 0.f;   // gate row-sum + swizzle partner for step s-2
  float w_[4], b_[4], nw_[4], nb_[4];

  auto clampi = [](int x){ return x > (S_LEN-4) ? (S_LEN-4) : x; };

  auto LOADE = [&](const i32x4& q4, float (&wv)[4], float (&bv)[4]){
#pragma unroll
    for (int k=0;k<4;++k){ wv[k] = emb[q4[k]*64 + d]; bv[k] = emb[q4[k]*64 + 32 + d]; }
  };

  // one fused pipeline body for step s (R3-exact H numerics)
  auto BODY = [&](int s, float wv, float bpv){
    // ---- P(s-1): gate partials + DPP folds (uses hr,hi = h(s-1)) ----
    float p0 = __builtin_fmaf(hr, wgr[0], hi*wgi[0]);
    float p1 = __builtin_fmaf(hr, wgr[1], hi*wgi[1]);
    float p2 = __builtin_fmaf(hr, wgr[2], hi*wgi[2]);
    float p3 = __builtin_fmaf(hr, wgr[3], hi*wgi[3]);
    float m01 = b0 ? p1 : p0;
    float t01 = b0 ? p0 : p1;
    m01 += dppmov<0xB1>(t01);              // quad_perm xor1
    float m23 = b0 ? p3 : p2;
    float t23 = b0 ? p2 : p3;
    m23 += dppmov<0xB1>(t23);
    float mm = b1 ? m23 : m01;
    float tt = b1 ? m01 : m23;
    mm += dppmov<0x4E>(tt);                // quad_perm xor2
    mm += dppmov<0x124>(mm);               // row_ror:4
    mm += dppmov<0x128>(mm);               // row_ror:8  -> row-16 sum for head l&3
    // ---- H(s) part 1: theta construction + range reduction (independent of P) ----
    float invw = __builtin_amdgcn_rcpf(1.f + __builtin_fabsf(wv));
    float tp = (float)s * PHI_F;
    float thr = __builtin_fmaf(hr, invw, bpv) + tp;
    float thi = __builtin_fmaf(hi, invw, bpv) + tp;
    float qr = __builtin_floorf(thr * INV2PI);
    float rr = __builtin_fmaf(-qr, TWOPI_F, thr);
    rr = (rr < 0.f) ? (rr + TWOPI_F) : rr;
    rr = (rr >= TWOPI_F) ? (rr - TWOPI_F) : rr;
    float qi = __builtin_floorf(thi * INV2PI);
    float ri = __builtin_fmaf(-qi, TWOPI_F, thi);
    ri = (ri < 0.f) ? (ri + TWOPI_F) : ri;
    ri = (ri >= TWOPI_F) ? (ri - TWOPI_F) : ri;
    // ---- X(s-1): issue xor16 swizzle (mm ready by now; consumed next body) ----
    float swA = swz<0x401F>(mm);
    // ---- H(s) part 2: trig + rotation combine ----
    float sr = sin2pi(rr * INV2PI), cr = cos2pi(rr * INV2PI);
    float si = sin2pi(ri * INV2PI), ci = cos2pi(ri * INV2PI);
    float nhr = __builtin_fmaf(cr, ci, -(sr*si));
    float nhi = __builtin_fmaf(cr, si,  sr*ci);
    // ---- Z(s-2): consume swizzle issued one body ago ----
    int jm2 = s - 2;
    if (jm2 >= sw){
      float z = mmB + swB;                 // full 32-lane (=64-component) sum
      float g_ = 1.f / (1.f + __expf(-(z + bgl)));
      mr = __builtin_fmaf(dk, mr, g_*h2r);
      mi = __builtin_fmaf(dk, mi, g_*h2i);
      float outr = __builtin_fmaf(es, mr, h2r);
      float outi = __builtin_fmaf(es, mi, h2i);
      unsigned hw_; asm("v_cvt_pk_bf16_f32 %0, %1, %2" : "=v"(hw_) : "v"(outr), "v"(outi));
      float lr_ = outr - __uint_as_float(hw_ << 16);
      float li_ = outi - __uint_as_float(hw_ & 0xffff0000u);
      unsigned lw_; asm("v_cvt_pk_bf16_f32 %0, %1, %2" : "=v"(lw_) : "v"(lr_), "v"(li_));
      if (jm2 >= s0){ pco[(size_t)jm2*32] = hw_; plo[(size_t)jm2*32] = lw_; }
    }
    // ---- rotate latches ----
    mmB = mm; swB = swA;
    h2r = hr; h2i = hi;
    hr = nhr; hi = nhi;
  };

  // drain body: no H(s); P/X for step sl (= hr), Z for sl-1
  auto DRAIN = [&](int sl){
    float p0 = __builtin_fmaf(hr, wgr[0], hi*wgi[0]);
    float p1 = __builtin_fmaf(hr, wgr[1], hi*wgi[1]);
    float p2 = __builtin_fmaf(hr, wgr[2], hi*wgi[2]);
    float p3 = __builtin_fmaf(hr, wgr[3], hi*wgi[3]);
    float m01 = b0 ? p1 : p0;
    float t01 = b0 ? p0 : p1;
    m01 += dppmov<0xB1>(t01);
    float m23 = b0 ? p3 : p2;
    float t23 = b0 ? p2 : p3;
    m23 += dppmov<0xB1>(t23);
    float mm = b1 ? m23 : m01;
    float tt = b1 ? m01 : m23;
    mm += dppmov<0x4E>(tt);
    mm += dppmov<0x124>(mm);
    mm += dppmov<0x128>(mm);
    float swA = swz<0x401F>(mm);
    int jm2 = sl - 1;
    if (jm2 >= sw){
      float z = mmB + swB;
      float g_ = 1.f / (1.f + __expf(-(z + bgl)));
      mr = __builtin_fmaf(dk, mr, g_*h2r);
      mi = __builtin_fmaf(dk, mi, g_*h2i);
      float outr = __builtin_fmaf(es, mr, h2r);
      float outi = __builtin_fmaf(es, mi, h2i);
      unsigned hw_; asm("v_cvt_pk_bf16_f32 %0, %1, %2" : "=v"(hw_) : "v"(outr), "v"(outi));
      float lr_ = outr - __uint_as_float(hw_ << 16);
      float li_ = outi - __uint_as_float(hw_ & 0xffff0000u);
      unsigned lw_; asm("v_cvt_pk_bf16_f32 %0, %1, %2" : "=v"(lw_) : "v"(lr_), "v"(li_));
      if (jm2 >= s0){ pco[(size_t)jm2*32] = hw_; plo[(size_t)jm2*32] = lw_; }
    }
    mmB = mm; swB = swA;
    h2r = hr; h2i = hi;
  };

  // ---- prologue: emb group0 -> w_, group1 -> nw_, ids group2 -> qn ----
  {
    i32x4 q0v = *(const i32x4*)(idb + sw);
    LOADE(q0v, w_, b_);
  }
  {
    i32x4 q1v = *(const i32x4*)(idb + clampi(sw + 4));
    LOADE(q1v, nw_, nb_);
  }
  i32x4 qn = *(const i32x4*)(idb + clampi(sw + 8));

  // fill: bodies sw, sw+1
  BODY(sw,   w_[0], b_[0]);
  BODY(sw+1, w_[1], b_[1]);

  // main: quads offset by 2 (R9-proven ring structure)
  for (int it = 0; it < nq-1; ++it){
    int j0 = sw + 2 + 4*it;
    BODY(j0,   w_[2], b_[2]);
    BODY(j0+1, w_[3], b_[3]);
#pragma unroll
    for (int k=0;k<4;++k){ w_[k] = nw_[k]; b_[k] = nb_[k]; }
    {
      i32x4 qq = qn;
      LOADE(qq, nw_, nb_);
      qn = *(const i32x4*)(idb + clampi(sw + 4*(it+3)));
    }
    BODY(j0+2, w_[0], b_[0]);
    BODY(j0+3, w_[1], b_[1]);
  }
  // tail bodies
  BODY(send-2, w_[2], b_[2]);
  BODY(send-1, w_[3], b_[3]);
  // drain: Z(send-2), then Z(send-1)
  DRAIN(send-1);   // P/X recompute for send-1 (harmless), Z(send-2)
  {                // final Z(send-1)
    float z = mmB + swB;
    float g_ = 1.f / (1.f + __expf(-(z + bgl)));
    mr = __builtin_fmaf(dk, mr, g_*h2r);
    mi = __builtin_fmaf(dk, mi, g_*h2i);
    float outr = __builtin_fmaf(es, mr, h2r);
    float outi = __builtin_fmaf(es, mi, h2i);
    unsigned hw_; asm("v_cvt_pk_bf16_f32 %0, %1, %2" : "=v"(hw_) : "v"(outr), "v"(outi));
    float lr_ = outr - __uint_as_float(hw_ << 16);
    float li_ = outi - __uint_as_float(hw_ & 0xffff0000u);
    unsigned lw_; asm("v_cvt_pk_bf16_f32 %0, %1, %2" : "=v"(lw_) : "v"(lr_), "v"(li_));
    pco[(size_t)(send-1)*32] = hw_; plo[(size_t)(send-1)*32] = lw_;
  }
}

// ---------------- projection: [32768,64] x [4096,64]^T, split-bf16 MFMA (unchanged, validated) ----------------
__global__ __launch_bounds__(256) void gemm_kernel(
    const ushort* __restrict__ chi, const ushort* __restrict__ clo,
    const ushort* __restrict__ whi, const ushort* __restrict__ wlo,
    const float* __restrict__ bout, float* __restrict__ out)
{
  __shared__ char lds[65536];  // A_hi | A_lo | W_hi | W_lo, 16KB each
  const int row0 = blockIdx.y * 128;
  const int v0   = blockIdx.x * 128;
  const int t = threadIdx.x;

  {
    const char* s0 = (const char*)(chi) + (size_t)row0 * 128;
    const char* s1 = (const char*)(clo) + (size_t)row0 * 128;
    const char* s2 = (const char*)(whi) + (size_t)v0 * 128;
    const char* s3 = (const char*)(wlo) + (size_t)v0 * 128;
    const char* srcs[4] = {s0, s1, s2, s3};
#pragma unroll
    for (int a2 = 0; a2 < 4; ++a2){
      char* dst = lds + a2 * 16384;
      const char* src = srcs[a2];
#pragma unroll
      for (int i = 0; i < 4; ++i){
        int id = t + 256 * i;          // 1024 chunks of 16B
        int r = id >> 3, ccol = id & 7;
        i32x4 vv = *(const i32x4*)(src + r*128 + ccol*16);
        *(i32x4*)(dst + r*128 + ((ccol ^ (r & 7)) * 16)) = vv;
      }
    }
  }
  __syncthreads();

  const int lane = t & 63;
  const int wid  = t >> 6;
  const int wr = (wid >> 1) * 64;
  const int wc = (wid & 1) * 64;
  const int lr = lane & 15;
  const int lk = lane >> 4;           // k-group 0..3

  f32x4 acc[4][4];
#pragma unroll
  for (int m = 0; m < 4; ++m)
#pragma unroll
    for (int n = 0; n < 4; ++n) acc[m][n] = (f32x4){0.f, 0.f, 0.f, 0.f};

  i32x2 afr[2][4][4];
#pragma unroll
  for (int hf = 0; hf < 2; ++hf){
    const char* Ab = lds + hf * 16384;
#pragma unroll
    for (int m = 0; m < 4; ++m){
      int row = wr + m*16 + lr;
      const char* rp = Ab + row * 128;
      int sw = (row & 7) << 1;
#pragma unroll
      for (int ks = 0; ks < 4; ++ks){
        int c8 = (ks*4 + lk) ^ sw;
        afr[hf][m][ks] = *(const i32x2*)(rp + c8 * 8);
      }
    }
  }
#pragma unroll
  for (int wh = 0; wh < 2; ++wh){
    const char* Bb = lds + 32768 + wh * 16384;
    i32x2 bfr[4][4];
#pragma unroll
    for (int n = 0; n < 4; ++n){
      int row = wc + n*16 + lr;
      const char* rp = Bb + row * 128;
      int sw = (row & 7) << 1;
#pragma unroll
      for (int ks = 0; ks < 4; ++ks){
        int c8 = (ks*4 + lk) ^ sw;
        bfr[n][ks] = *(const i32x2*)(rp + c8 * 8);
      }
    }
#pragma unroll
    for (int hf = 0; hf < 2; ++hf)
#pragma unroll
      for (int m = 0; m < 4; ++m)
#pragma unroll
        for (int n = 0; n < 4; ++n)
#pragma unroll
          for (int ks = 0; ks < 4; ++ks)
            asm("v_mfma_f32_16x16x16_bf16 %0, %1, %2, %0"
                : "+v"(acc[m][n]) : "v"(afr[hf][m][ks]), "v"(bfr[n][ks]));
  }

  // epilogue: C/D layout col = lane&15, row = (lane>>4)*4 + reg
#pragma unroll
  for (int n = 0; n < 4; ++n){
    float bias = bout[v0 + wc + n*16 + lr];
#pragma unroll
    for (int m = 0; m < 4; ++m){
      int gr = row0 + wr + m*16 + lk*4;
      float* op = out + (size_t)gr * 4096 + (v0 + wc + n*16 + lr);
#pragma unroll
      for (int rg = 0; rg < 4; ++rg){
        op[(size_t)rg * 4096] = acc[m][n][rg] + bias;
      }
    }
  }
}

extern "C" void kernel_launch(void* const* d_in, const int* in_sizes, int n_in,
                              void* d_out, int out_size, void* d_ws, size_t ws_size,
                              hipStream_t stream)
{
  const int*   ids  = (const int*)  d_in[0];
  const float* emb  = (const float*)d_in[1];
  const float* Wout = (const float*)d_in[2];
  const float* bout = (const float*)d_in[3];
  const float* Wg   = (const float*)d_in[4];
  const float* bg   = (const float*)d_in[5];
  const float* dlg  = (const float*)d_in[6];
  const float* esc  = (const float*)d_in[7];
  float* out = (float*)d_out;
  char* ws = (char*)d_ws;
  // ws layout: c_hi 4MB | c_lo 4MB | w_hi 512KB | w_lo 512KB  (9MB total)
  ushort* chi = (ushort*)(ws);
  ushort* clo = (ushort*)(ws + 4u*1024u*1024u);
  ushort* whi = (ushort*)(ws + 8u*1024u*1024u);
  ushort* wlo = (ushort*)(ws + 8u*1024u*1024u + 512u*1024u);

  // blocks 0..255: scan (32 chunks x 8 batch-pairs); 256..1279: W split (k''-permuted)
  scan_kernel<<<dim3(1280), dim3(64), 0, stream>>>(ids, emb, Wg, bg, dlg, esc,
                                                   chi, clo, Wout, whi, wlo);
  gemm_kernel<<<dim3(32, 256), dim3(256), 0, stream>>>(chi, clo, whi, wlo, bout, out);
}